// Round 12
// baseline (107.330 us; speedup 1.0000x reference)
//
#include <hip/hip_runtime.h>
#include <utility>

// EquivariantProductBasisBlock (MACE-style) for gfx950 — round 12.
// R11 learned: linear's LDS variant is ds_read-issue bound (~15us of b128
// issue per CU) — scalar-load, prefetch and LDS variants all ~20us. R12:
// linear via MFMA bf16 split-precision (x=hi+lo, 4 products/K-chunk ->
// ~2^-16 relative error). Basis epilogue writes B as bf16 hi/lo planes
// [m][4096][128]; wt_pack pre-transposes/splits lw0/lw1 to [f][c]; linear =
// 16x16 tiles, K=128 in 4 chunks x 4 MFMA. Fixed 62us tax (44us d_ws poison
// fill + 18us replay) is outside our control; kernel budget 41us -> ~22us.

#define NN 4096
#define NC 128
#define NE 10

typedef float v2f __attribute__((ext_vector_type(2)));
typedef __bf16 bf16x8 __attribute__((ext_vector_type(8)));
typedef float f32x4 __attribute__((ext_vector_type(4)));

__device__ __forceinline__ v2f ld2(const float* p) {
  return *reinterpret_cast<const v2f*>(p);
}
__device__ __forceinline__ v2f cfma(float c, v2f x, v2f a) {
  v2f cc = {c, c};
  return __builtin_elementwise_fma(cc, x, a);
}
__device__ __forceinline__ v2f vfma(v2f w, v2f x, v2f a) {
  return __builtin_elementwise_fma(w, x, a);
}

// round-to-nearest-even float -> bf16 bits, and back
__device__ __forceinline__ unsigned short f2bf(float x) {
  unsigned int u = __float_as_uint(x);
  unsigned int r = (u + 0x7FFFu + ((u >> 16) & 1u)) >> 16;
  return (unsigned short)r;
}
__device__ __forceinline__ float bf2f(unsigned short h) {
  return __uint_as_float(((unsigned int)h) << 16);
}

// ---------------------------- static_for ---------------------------------------
template<typename F, int... Is>
__device__ __forceinline__ void sfor_impl(F&& f, std::integer_sequence<int, Is...>) {
  (f(std::integral_constant<int, Is>{}), ...);
}
template<int N, typename F>
__device__ __forceinline__ void sfor(F&& f) {
  sfor_impl((F&&)f, std::make_integer_sequence<int, N>{});
}

// ---------------------------- CG metadata (constexpr) --------------------------
constexpr int T_L1c[19]  = {0,0,0,1,1,1,1,1,1,1,2,2,2,2,2,2,2,2,3};
constexpr int T_L2c[19]  = {0,1,2,0,1,1,1,2,2,2,0,1,1,1,2,2,2,2,2};
constexpr int T_L3c[19]  = {0,1,2,1,0,1,2,1,2,3,2,1,2,3,0,1,2,3,1};
constexpr int T_OFFc[19] = {0,1,10,35,44,53,80,125,170,245,350,375,420,495,600,625,700,825,1000};
constexpr int AOFFc[3]   = {0,1,4};

constexpr int P2U_L1c[7]  = {0,0,1,1,1,2,2};
constexpr int P2U_L2c[7]  = {0,1,1,1,2,2,2};
constexpr int P2U_LOc[7]  = {0,1,0,1,1,0,1};
constexpr int P2U_TBLc[7] = {0,1,4,5,7,14,15};
constexpr int P2U_WAc[7]  = {0,1,3,4,5,7,8};
constexpr int P2U_WBc[7]  = {-1,2,-1,-1,6,-1,-1};

constexpr int K_L1c[18]  = {0,0,0,1,1,1,1,1,1,1,2,2,2,2,2,2,2,2};
constexpr int K_L2c[18]  = {0,1,2,0,1,1,1,2,2,2,0,1,1,1,2,2,2,2};
constexpr int K_L12c[18] = {0,1,2,1,0,1,2,1,2,3,2,1,2,3,0,1,2,3};

constexpr int   TT_CANONc[18] = {0,1,2,1,4,5,6,7,8,9,2,7,8,9,14,15,16,17};
constexpr float TT_SGNc[18]   = {1,1,1,1,1,1,1,1,1,1,1,1,-1,1,1,1,1,1};
constexpr int CANONc[13] = {0,1,2,4,5,6,7,8,9,14,15,16,17};
constexpr int CONS2c[13] = {-1,3,10,-1,-1,-1,11,12,13,-1,-1,-1,-1};

constexpr int P3_STARTc[19] = {0,2,6,9,13,15,19,22,26,29,30,33,37,40,41,43,47,50,51};
constexpr int P3_L3c[51] = {
  0,1,  0,1,1,2,  1,2,2,  0,1,1,2,  0,1,  0,1,1,2,  1,2,2,  0,1,1,2,  1,2,2,
  2,  1,2,2,  0,1,1,2,  1,2,2,  2,  0,1,  0,1,1,2,  1,2,2,  2 };
constexpr int P3_LOc[51] = {
  0,1,  1,0,1,1,  1,0,1,  1,0,1,1,  0,1,  1,0,1,1,  1,0,1,  1,0,1,1,  1,0,1,
  1,  1,0,1,  1,0,1,1,  1,0,1,  1,  0,1,  1,0,1,1,  1,0,1,  1 };
constexpr int P3_TBLc[51] = {
  0,1,  3,4,5,7,  11,14,15,  3,4,5,7,  0,1,  3,4,5,7,  11,14,15,  3,4,5,7,
  11,14,15,  18,  11,14,15,  3,4,5,7,  11,14,15,  18,  0,1,  3,4,5,7,
  11,14,15,  18 };

// ---------------------------- constexpr CG computation -------------------------
constexpr double cfact(int n) { double r = 1.0; for (int i = 2; i <= n; ++i) r *= i; return r; }
constexpr double csqrt(double x) {
  if (x <= 0.0) return 0.0;
  double r = x > 1.0 ? x : 1.0;
  for (int i = 0; i < 64; ++i) r = 0.5 * (r + x / r);
  return r;
}
constexpr double su2cg(int j1, int m1, int j2, int m2, int j3, int m3) {
  if (m3 != m1 + m2) return 0.0;
  int vmin = -j1 + j2 + m3; if (-j1 + m1 > vmin) vmin = -j1 + m1; if (vmin < 0) vmin = 0;
  int vmax = j2 + j3 + m1; if (j3 - j1 + j2 < vmax) vmax = j3 - j1 + j2; if (j3 + m3 < vmax) vmax = j3 + m3;
  double C = csqrt((2.0 * j3 + 1.0)
                   * cfact(j3 + j1 - j2) * cfact(j3 - j1 + j2) * cfact(j1 + j2 - j3)
                   * cfact(j3 + m3) * cfact(j3 - m3)
                   / (cfact(j1 + j2 + j3 + 1) * cfact(j1 - m1) * cfact(j1 + m1)
                      * cfact(j2 - m2) * cfact(j2 + m2)));
  double S = 0.0;
  for (int v = vmin; v <= vmax; ++v) {
    double sgn = ((v + j2 + m2) & 1) ? -1.0 : 1.0;
    S += sgn * cfact(j2 + j3 + m1 - v) * cfact(j1 - m1 + v)
         / (cfact(v) * cfact(j3 - j1 + j2 - v) * cfact(j3 + m3 - v) * cfact(v + j1 - j2 - m3));
  }
  return C * S;
}

struct Cx { double re, im; };
constexpr Cx cxmul(Cx a, Cx b) { return Cx{a.re * b.re - a.im * b.im, a.re * b.im + a.im * b.re}; }
struct Row { int cnt; int col[2]; Cx v[2]; };

constexpr Row c2r_row(int l, int r) {
  Row out{0, {0, 0}, {{0, 0}, {0, 0}}};
  constexpr double is2 = 0.70710678118654752440;
  const int m = r - l;
  if (m < 0) {
    out.cnt = 2;
    out.col[0] = l - m; out.v[0] = Cx{is2, 0.0};
    out.col[1] = l + m; out.v[1] = Cx{0.0, -is2};
  } else if (m == 0) {
    out.cnt = 1; out.col[0] = l; out.v[0] = Cx{1.0, 0.0};
  } else {
    const double sgn = (m & 1) ? -1.0 : 1.0;
    out.cnt = 2;
    out.col[0] = l + m; out.v[0] = Cx{sgn * is2, 0.0};
    out.col[1] = l - m; out.v[1] = Cx{0.0, sgn * is2};
  }
  const int ph = l & 3;
  for (int a = 0; a < out.cnt; ++a) {
    Cx v = out.v[a];
    out.v[a] = (ph == 0) ? v
             : (ph == 1) ? Cx{v.im, -v.re}
             : (ph == 2) ? Cx{-v.re, -v.im}
                         : Cx{-v.im, v.re};
  }
  return out;
}

struct CGAll { float v[1105]; };
constexpr CGAll make_cg() {
  CGAll R{};
  for (int t = 0; t < 19; ++t) {
    const int l1 = T_L1c[t], l2 = T_L2c[t], l3 = T_L3c[t], off = T_OFFc[t];
    const int d1 = 2 * l1 + 1, d2 = 2 * l2 + 1, d3 = 2 * l3 + 1;
    double tmp[175] = {};
    for (int i = 0; i < d1; ++i) {
      const int m1 = i - l1;
      const Row r1 = c2r_row(l1, i);
      for (int k = 0; k < d2; ++k) {
        const int m2 = k - l2, m3 = m1 + m2;
        if (m3 < -l3 || m3 > l3) continue;
        const double cc = su2cg(l1, m1, l2, m2, l3, m3);
        if (cc == 0.0) continue;
        const Row r2 = c2r_row(l2, k);
        const Row r3 = c2r_row(l3, m3 + l3);
        for (int a = 0; a < r1.cnt; ++a)
          for (int b = 0; b < r2.cnt; ++b) {
            const Cx q12 = cxmul(r1.v[a], r2.v[b]);
            for (int cdx = 0; cdx < r3.cnt; ++cdx) {
              const double re = q12.re * r3.v[cdx].re + q12.im * r3.v[cdx].im;
              tmp[(r1.col[a] * d2 + r2.col[b]) * d3 + r3.col[cdx]] += re * cc;
            }
          }
      }
    }
    const int sz = d1 * d2 * d3;
    for (int e = 0; e < sz; ++e) R.v[off + e] = (float)tmp[e];
  }
  return R;
}
constexpr CGAll CG_ALL = make_cg();

constexpr bool check_cg_sym() {
  for (int t = 0; t < 18; ++t) {
    const int tc = TT_CANONc[t];
    if (tc == t) continue;
    const int l1 = K_L1c[t], l2 = K_L2c[t], l12 = K_L12c[t];
    const int d1 = 2*l1+1, d2 = 2*l2+1, d12 = 2*l12+1;
    for (int i = 0; i < d1; ++i)
      for (int j = 0; j < d2; ++j)
        for (int k = 0; k < d12; ++k) {
          float a = CG_ALL.v[T_OFFc[t]  + (i*d2 + j)*d12 + k];
          float b = TT_SGNc[t] * CG_ALL.v[T_OFFc[tc] + (j*d1 + i)*d12 + k];
          float d = a - b; if (d < 0) d = -d;
          if (d > 1e-5f) return false;
        }
  }
  return true;
}
static_assert(check_cg_sym(), "CG exchange symmetry violated");

// ============================ basis kernel =====================================
// Same compute as R9; epilogue writes bf16 hi/lo planes Ahi/Alo[m][n][c].
__global__ __launch_bounds__(256) void epb_basis(
    const float* __restrict__ nf,      // [N, C, 9]
    const float* __restrict__ w1,      // [E, 2, C]
    const float* __restrict__ w2,      // [E, 9, C]
    const float* __restrict__ w3,      // [E, 51, C]
    const int*   __restrict__ species, // [N]
    unsigned int* __restrict__ AhiW,   // [4][N][C] bf16 viewed as uint pairs
    unsigned int* __restrict__ AloW)
{
  const int t  = threadIdx.x;
  const int nb = blockIdx.x * 4;
  const int nl = t >> 6;               // wave-uniform node
  const int c0 = (t & 63) * 2;         // channel pair
  const int n  = nb + nl;
  const int s  = species[n];

  const float* ap = nf + ((size_t)n * NC + c0) * 9;
  v2f A[9];
  sfor<9>([&](auto I) { A[I.value] = v2f{ap[I.value], ap[I.value + 9]}; });

  const float* w1p = w1 + (size_t)s * 2  * NC + c0;
  const float* w2p = w2 + (size_t)s * 9  * NC + c0;
  const float* w3p = w3 + (size_t)s * 51 * NC + c0;

  v2f B[4];
  {
    const v2f wa = ld2(w1p), wb = ld2(w1p + NC);
    B[0] = wa * A[0];
    B[1] = wb * A[1];
    B[2] = wb * A[2];
    B[3] = wb * A[3];
  }

  sfor<7>([&](auto P) {
    constexpr int p  = P.value;
    constexpr int l1 = P2U_L1c[p], l2 = P2U_L2c[p], lo = P2U_LOc[p];
    constexpr int d1 = 2*l1+1, d2 = 2*l2+1, dl = 2*lo+1;
    constexpr int off = T_OFFc[P2U_TBLc[p]];
    v2f w = ld2(w2p + P2U_WAc[p] * NC);
    if constexpr (P2U_WBc[p] >= 0) w = w + ld2(w2p + P2U_WBc[p] * NC);
    sfor<dl>([&](auto Kk) {
      constexpr int k = Kk.value;
      v2f v = {0.f, 0.f};
      sfor<d1>([&](auto I) {
        sfor<d2>([&](auto J) {
          constexpr float cgc = CG_ALL.v[off + (I.value * d2 + J.value) * dl + k];
          if constexpr (cgc != 0.0f) {
            constexpr int ia = AOFFc[l1] + I.value, ja = AOFFc[l2] + J.value;
            constexpr int x = ia < ja ? ia : ja, y = ia < ja ? ja : ia;
            v = cfma(cgc, A[x] * A[y], v);
          }
        });
      });
      B[lo + k] = vfma(w, v, B[lo + k]);
    });
  });

  sfor<13>([&](auto CI) {
    constexpr int tk  = CANONc[CI.value];
    constexpr int l1  = K_L1c[tk], l2 = K_L2c[tk], l12 = K_L12c[tk];
    constexpr int d1  = 2*l1+1, d2 = 2*l2+1, d12 = 2*l12+1;
    constexpr int off = T_OFFc[tk];
    v2f tt[d12];
    sfor<d12>([&](auto Kk) {
      constexpr int k = Kk.value;
      v2f v = {0.f, 0.f};
      sfor<d1>([&](auto I) {
        sfor<d2>([&](auto J) {
          constexpr float cgc = CG_ALL.v[off + (I.value * d2 + J.value) * d12 + k];
          if constexpr (cgc != 0.0f) {
            constexpr int ia = AOFFc[l1] + I.value, ja = AOFFc[l2] + J.value;
            constexpr int x = ia < ja ? ia : ja, y = ia < ja ? ja : ia;
            v = cfma(cgc, A[x] * A[y], v);
          }
        });
      });
      tt[k] = v;
    });

    auto consume = [&](auto TK, auto SG) {
      constexpr int tkey = TK.value;
      constexpr float sgn = (float)SG.value;
      constexpr int pcnt = P3_STARTc[tkey + 1] - P3_STARTc[tkey];
      sfor<pcnt>([&](auto PP) {
        constexpr int p  = P3_STARTc[tkey] + PP.value;
        constexpr int l3 = P3_L3c[p], lo = P3_LOc[p];
        constexpr int d3 = 2*l3+1, dl = 2*lo+1;
        constexpr int off2 = T_OFFc[P3_TBLc[p]];
        const v2f w = ld2(w3p + p * NC);
        sfor<dl>([&](auto M) {
          v2f v = {0.f, 0.f};
          sfor<d12>([&](auto Kk) {
            sfor<d3>([&](auto J) {
              constexpr float cgc = sgn * CG_ALL.v[off2 + (Kk.value * d3 + J.value) * dl + M.value];
              if constexpr (cgc != 0.0f)
                v = cfma(cgc, tt[Kk.value] * A[AOFFc[l3] + J.value], v);
            });
          });
          B[lo + M.value] = vfma(w, v, B[lo + M.value]);
        });
      });
    };
    consume(std::integral_constant<int, tk>{}, std::integral_constant<int, 1>{});
    constexpr int td = CONS2c[CI.value];
    if constexpr (td >= 0)
      consume(std::integral_constant<int, td>{},
              std::integral_constant<int, (int)TT_SGNc[td]>{});
  });

  // epilogue: bf16 split (hi + lo) into MFMA-friendly planes, coalesced dwords
  const int idx = n * 64 + (c0 >> 1);       // uint index within a plane
  sfor<4>([&](auto M) {
    constexpr int m = M.value;
    const float x0 = B[m].x, x1 = B[m].y;
    const unsigned short h0 = f2bf(x0), h1 = f2bf(x1);
    const unsigned short l0 = f2bf(x0 - bf2f(h0)), l1 = f2bf(x1 - bf2f(h1));
    AhiW[m * (NN * 64) + idx] = ((unsigned int)h1 << 16) | h0;
    AloW[m * (NN * 64) + idx] = ((unsigned int)l1 << 16) | l0;
  });
}

// ============================ weight pack ======================================
// Wt layout (ushort): [w0_hi][w0_lo][w1_hi][w1_lo], each [f][c] (transposed).
__global__ __launch_bounds__(256) void wt_pack(
    const float* __restrict__ lw0, const float* __restrict__ lw1,
    unsigned short* __restrict__ Wt)
{
  const int tid = blockIdx.x * 256 + threadIdx.x;  // 2 * 128 * 128 = 32768
  const int mat = tid >> 14;
  const int rr  = tid & 16383;
  const int f   = rr >> 7, c = rr & 127;
  const float x = (mat ? lw1 : lw0)[c * NC + f];
  const unsigned short h = f2bf(x);
  const unsigned short l = f2bf(x - bf2f(h));
  unsigned short* base = Wt + mat * 2 * (NC * NC);
  base[f * NC + c]           = h;
  base[NC * NC + f * NC + c] = l;
}

// ============================ MFMA linear ======================================
// Tile = 16 rows (nodes of one m-plane) x 16 features, K=128 in 4 chunks.
// Split precision: 4 MFMA per chunk (hh, hl, lh, ll). 8192 tiles, 4 waves/block.
__global__ __launch_bounds__(256) void epb_linear_mfma(
    const unsigned short* __restrict__ Ahi,   // [4][N][C] bf16
    const unsigned short* __restrict__ Alo,
    const unsigned short* __restrict__ Wt,    // [4][128][128] bf16 (f-major)
    float* __restrict__ out)                  // [N, F, 4]
{
  const int lane = threadIdx.x & 63;
  const int T = blockIdx.x * 4 + (threadIdx.x >> 6);   // 0..8191
  const int m  = T >> 11;                               // plane 0..3
  const int r  = T & 2047;
  const int n0 = (r >> 3) * 16;
  const int f0 = (r & 7) * 16;

  const unsigned short* Whi = Wt + (m == 0 ? 0 : 2) * (NC * NC);
  const unsigned short* Wlo = Whi + NC * NC;

  const int row  = lane & 15;   // A: M-row / W: N-col / C/D: N-col
  const int quad = lane >> 4;

  const unsigned short* ah = Ahi + (size_t)m * (NN * NC) + (n0 + row) * NC + quad * 8;
  const unsigned short* al = Alo + (size_t)m * (NN * NC) + (n0 + row) * NC + quad * 8;
  const unsigned short* wh = Whi + (f0 + row) * NC + quad * 8;
  const unsigned short* wl = Wlo + (f0 + row) * NC + quad * 8;

  f32x4 acc = {0.f, 0.f, 0.f, 0.f};
  sfor<4>([&](auto KC) {
    constexpr int c0 = KC.value * 32;
    const bf16x8 a_h = *reinterpret_cast<const bf16x8*>(ah + c0);
    const bf16x8 a_l = *reinterpret_cast<const bf16x8*>(al + c0);
    const bf16x8 w_h = *reinterpret_cast<const bf16x8*>(wh + c0);
    const bf16x8 w_l = *reinterpret_cast<const bf16x8*>(wl + c0);
    acc = __builtin_amdgcn_mfma_f32_16x16x32_bf16(a_h, w_h, acc, 0, 0, 0);
    acc = __builtin_amdgcn_mfma_f32_16x16x32_bf16(a_h, w_l, acc, 0, 0, 0);
    acc = __builtin_amdgcn_mfma_f32_16x16x32_bf16(a_l, w_h, acc, 0, 0, 0);
    acc = __builtin_amdgcn_mfma_f32_16x16x32_bf16(a_l, w_l, acc, 0, 0, 0);
  });

  const float s4 = 0.08838834764831845f;  // 1/sqrt(128)
  const int f = f0 + row;                 // C/D col = lane&15
  const int nbase = n0 + quad * 4;        // C/D row = quad*4 + reg
  sfor<4>([&](auto R) {
    out[(size_t)(nbase + R.value) * 512 + f * 4 + m] = acc[R.value] * s4;
  });
}

// ------------------------------- launcher --------------------------------------
extern "C" void kernel_launch(void* const* d_in, const int* in_sizes, int n_in,
                              void* d_out, int out_size, void* d_ws, size_t ws_size,
                              hipStream_t stream) {
  const float* nf  = (const float*)d_in[0];
  const float* w1  = (const float*)d_in[1];
  const float* w2  = (const float*)d_in[2];
  const float* w3  = (const float*)d_in[3];
  const float* lw0 = (const float*)d_in[4];
  const float* lw1 = (const float*)d_in[5];
  const int*   spc = (const int*)  d_in[6];
  float* out = (float*)d_out;

  unsigned short* Ahi = (unsigned short*)d_ws;       // 4 planes x N x C bf16 = 4 MB
  unsigned short* Alo = Ahi + (size_t)4 * NN * NC;   // 4 MB
  unsigned short* Wt  = Alo + (size_t)4 * NN * NC;   // 128 KB
  (void)ws_size; (void)in_sizes; (void)n_in; (void)out_size;

  hipLaunchKernelGGL(wt_pack, dim3(32768 / 256), dim3(256), 0, stream,
                     lw0, lw1, Wt);
  hipLaunchKernelGGL(epb_basis, dim3(NN / 4), dim3(256), 0, stream,
                     nf, w1, w2, w3, spc, (unsigned int*)Ahi, (unsigned int*)Alo);
  hipLaunchKernelGGL(epb_linear_mfma, dim3(8192 / 4), dim3(256), 0, stream,
                     Ahi, Alo, Wt, out);
}

// Round 13
// 105.761 us; speedup vs baseline: 1.0148x; 1.0148x over previous
//
#include <hip/hip_runtime.h>
#include <utility>

// EquivariantProductBasisBlock (MACE-style) for gfx950 — round 13.
// R12 learned: MFMA linear is correct & fast but the plumbing (3rd launch +
// 16MB Bws HBM round-trip) ate the win. R13: ONE fused kernel — basis (R9 v2f
// form, wave=node) writes bf16 hi/lo planes to LDS (16x136-padded, bank-
// uniform), barrier, then the SAME waves run the R12-validated MFMA tiles.
// Rows 8..15 of each 16-row tile are garbage-but-discarded (MFMA rows are
// separable). wt_pack (128KB) kept. Fixed ~62us harness tax (268MB d_ws
// re-poison fill + replay overhead) is outside kernel control.

#define NN 4096
#define NC 128
#define NE 10

typedef float v2f __attribute__((ext_vector_type(2)));
typedef __bf16 bf16x8 __attribute__((ext_vector_type(8)));
typedef float f32x4 __attribute__((ext_vector_type(4)));

__device__ __forceinline__ v2f ld2(const float* p) {
  return *reinterpret_cast<const v2f*>(p);
}
__device__ __forceinline__ v2f cfma(float c, v2f x, v2f a) {
  v2f cc = {c, c};
  return __builtin_elementwise_fma(cc, x, a);
}
__device__ __forceinline__ v2f vfma(v2f w, v2f x, v2f a) {
  return __builtin_elementwise_fma(w, x, a);
}

__device__ __forceinline__ unsigned short f2bf(float x) {
  unsigned int u = __float_as_uint(x);
  unsigned int r = (u + 0x7FFFu + ((u >> 16) & 1u)) >> 16;
  return (unsigned short)r;
}
__device__ __forceinline__ float bf2f(unsigned short h) {
  return __uint_as_float(((unsigned int)h) << 16);
}

// ---------------------------- static_for ---------------------------------------
template<typename F, int... Is>
__device__ __forceinline__ void sfor_impl(F&& f, std::integer_sequence<int, Is...>) {
  (f(std::integral_constant<int, Is>{}), ...);
}
template<int N, typename F>
__device__ __forceinline__ void sfor(F&& f) {
  sfor_impl((F&&)f, std::make_integer_sequence<int, N>{});
}

// ---------------------------- CG metadata (constexpr) --------------------------
constexpr int T_L1c[19]  = {0,0,0,1,1,1,1,1,1,1,2,2,2,2,2,2,2,2,3};
constexpr int T_L2c[19]  = {0,1,2,0,1,1,1,2,2,2,0,1,1,1,2,2,2,2,2};
constexpr int T_L3c[19]  = {0,1,2,1,0,1,2,1,2,3,2,1,2,3,0,1,2,3,1};
constexpr int T_OFFc[19] = {0,1,10,35,44,53,80,125,170,245,350,375,420,495,600,625,700,825,1000};
constexpr int AOFFc[3]   = {0,1,4};

constexpr int P2U_L1c[7]  = {0,0,1,1,1,2,2};
constexpr int P2U_L2c[7]  = {0,1,1,1,2,2,2};
constexpr int P2U_LOc[7]  = {0,1,0,1,1,0,1};
constexpr int P2U_TBLc[7] = {0,1,4,5,7,14,15};
constexpr int P2U_WAc[7]  = {0,1,3,4,5,7,8};
constexpr int P2U_WBc[7]  = {-1,2,-1,-1,6,-1,-1};

constexpr int K_L1c[18]  = {0,0,0,1,1,1,1,1,1,1,2,2,2,2,2,2,2,2};
constexpr int K_L2c[18]  = {0,1,2,0,1,1,1,2,2,2,0,1,1,1,2,2,2,2};
constexpr int K_L12c[18] = {0,1,2,1,0,1,2,1,2,3,2,1,2,3,0,1,2,3};

constexpr int   TT_CANONc[18] = {0,1,2,1,4,5,6,7,8,9,2,7,8,9,14,15,16,17};
constexpr float TT_SGNc[18]   = {1,1,1,1,1,1,1,1,1,1,1,1,-1,1,1,1,1,1};
constexpr int CANONc[13] = {0,1,2,4,5,6,7,8,9,14,15,16,17};
constexpr int CONS2c[13] = {-1,3,10,-1,-1,-1,11,12,13,-1,-1,-1,-1};

constexpr int P3_STARTc[19] = {0,2,6,9,13,15,19,22,26,29,30,33,37,40,41,43,47,50,51};
constexpr int P3_L3c[51] = {
  0,1,  0,1,1,2,  1,2,2,  0,1,1,2,  0,1,  0,1,1,2,  1,2,2,  0,1,1,2,  1,2,2,
  2,  1,2,2,  0,1,1,2,  1,2,2,  2,  0,1,  0,1,1,2,  1,2,2,  2 };
constexpr int P3_LOc[51] = {
  0,1,  1,0,1,1,  1,0,1,  1,0,1,1,  0,1,  1,0,1,1,  1,0,1,  1,0,1,1,  1,0,1,
  1,  1,0,1,  1,0,1,1,  1,0,1,  1,  0,1,  1,0,1,1,  1,0,1,  1 };
constexpr int P3_TBLc[51] = {
  0,1,  3,4,5,7,  11,14,15,  3,4,5,7,  0,1,  3,4,5,7,  11,14,15,  3,4,5,7,
  11,14,15,  18,  11,14,15,  3,4,5,7,  11,14,15,  18,  0,1,  3,4,5,7,
  11,14,15,  18 };

// ---------------------------- constexpr CG computation -------------------------
constexpr double cfact(int n) { double r = 1.0; for (int i = 2; i <= n; ++i) r *= i; return r; }
constexpr double csqrt(double x) {
  if (x <= 0.0) return 0.0;
  double r = x > 1.0 ? x : 1.0;
  for (int i = 0; i < 64; ++i) r = 0.5 * (r + x / r);
  return r;
}
constexpr double su2cg(int j1, int m1, int j2, int m2, int j3, int m3) {
  if (m3 != m1 + m2) return 0.0;
  int vmin = -j1 + j2 + m3; if (-j1 + m1 > vmin) vmin = -j1 + m1; if (vmin < 0) vmin = 0;
  int vmax = j2 + j3 + m1; if (j3 - j1 + j2 < vmax) vmax = j3 - j1 + j2; if (j3 + m3 < vmax) vmax = j3 + m3;
  double C = csqrt((2.0 * j3 + 1.0)
                   * cfact(j3 + j1 - j2) * cfact(j3 - j1 + j2) * cfact(j1 + j2 - j3)
                   * cfact(j3 + m3) * cfact(j3 - m3)
                   / (cfact(j1 + j2 + j3 + 1) * cfact(j1 - m1) * cfact(j1 + m1)
                      * cfact(j2 - m2) * cfact(j2 + m2)));
  double S = 0.0;
  for (int v = vmin; v <= vmax; ++v) {
    double sgn = ((v + j2 + m2) & 1) ? -1.0 : 1.0;
    S += sgn * cfact(j2 + j3 + m1 - v) * cfact(j1 - m1 + v)
         / (cfact(v) * cfact(j3 - j1 + j2 - v) * cfact(j3 + m3 - v) * cfact(v + j1 - j2 - m3));
  }
  return C * S;
}

struct Cx { double re, im; };
constexpr Cx cxmul(Cx a, Cx b) { return Cx{a.re * b.re - a.im * b.im, a.re * b.im + a.im * b.re}; }
struct Row { int cnt; int col[2]; Cx v[2]; };

constexpr Row c2r_row(int l, int r) {
  Row out{0, {0, 0}, {{0, 0}, {0, 0}}};
  constexpr double is2 = 0.70710678118654752440;
  const int m = r - l;
  if (m < 0) {
    out.cnt = 2;
    out.col[0] = l - m; out.v[0] = Cx{is2, 0.0};
    out.col[1] = l + m; out.v[1] = Cx{0.0, -is2};
  } else if (m == 0) {
    out.cnt = 1; out.col[0] = l; out.v[0] = Cx{1.0, 0.0};
  } else {
    const double sgn = (m & 1) ? -1.0 : 1.0;
    out.cnt = 2;
    out.col[0] = l + m; out.v[0] = Cx{sgn * is2, 0.0};
    out.col[1] = l - m; out.v[1] = Cx{0.0, sgn * is2};
  }
  const int ph = l & 3;
  for (int a = 0; a < out.cnt; ++a) {
    Cx v = out.v[a];
    out.v[a] = (ph == 0) ? v
             : (ph == 1) ? Cx{v.im, -v.re}
             : (ph == 2) ? Cx{-v.re, -v.im}
                         : Cx{-v.im, v.re};
  }
  return out;
}

struct CGAll { float v[1105]; };
constexpr CGAll make_cg() {
  CGAll R{};
  for (int t = 0; t < 19; ++t) {
    const int l1 = T_L1c[t], l2 = T_L2c[t], l3 = T_L3c[t], off = T_OFFc[t];
    const int d1 = 2 * l1 + 1, d2 = 2 * l2 + 1, d3 = 2 * l3 + 1;
    double tmp[175] = {};
    for (int i = 0; i < d1; ++i) {
      const int m1 = i - l1;
      const Row r1 = c2r_row(l1, i);
      for (int k = 0; k < d2; ++k) {
        const int m2 = k - l2, m3 = m1 + m2;
        if (m3 < -l3 || m3 > l3) continue;
        const double cc = su2cg(l1, m1, l2, m2, l3, m3);
        if (cc == 0.0) continue;
        const Row r2 = c2r_row(l2, k);
        const Row r3 = c2r_row(l3, m3 + l3);
        for (int a = 0; a < r1.cnt; ++a)
          for (int b = 0; b < r2.cnt; ++b) {
            const Cx q12 = cxmul(r1.v[a], r2.v[b]);
            for (int cdx = 0; cdx < r3.cnt; ++cdx) {
              const double re = q12.re * r3.v[cdx].re + q12.im * r3.v[cdx].im;
              tmp[(r1.col[a] * d2 + r2.col[b]) * d3 + r3.col[cdx]] += re * cc;
            }
          }
      }
    }
    const int sz = d1 * d2 * d3;
    for (int e = 0; e < sz; ++e) R.v[off + e] = (float)tmp[e];
  }
  return R;
}
constexpr CGAll CG_ALL = make_cg();

constexpr bool check_cg_sym() {
  for (int t = 0; t < 18; ++t) {
    const int tc = TT_CANONc[t];
    if (tc == t) continue;
    const int l1 = K_L1c[t], l2 = K_L2c[t], l12 = K_L12c[t];
    const int d1 = 2*l1+1, d2 = 2*l2+1, d12 = 2*l12+1;
    for (int i = 0; i < d1; ++i)
      for (int j = 0; j < d2; ++j)
        for (int k = 0; k < d12; ++k) {
          float a = CG_ALL.v[T_OFFc[t]  + (i*d2 + j)*d12 + k];
          float b = TT_SGNc[t] * CG_ALL.v[T_OFFc[tc] + (j*d1 + i)*d12 + k];
          float d = a - b; if (d < 0) d = -d;
          if (d > 1e-5f) return false;
        }
  }
  return true;
}
static_assert(check_cg_sym(), "CG exchange symmetry violated");

// ============================ weight pack ======================================
// Wt layout (ushort): [w0_hi][w0_lo][w1_hi][w1_lo], each [f][c] (transposed).
__global__ __launch_bounds__(256) void wt_pack(
    const float* __restrict__ lw0, const float* __restrict__ lw1,
    unsigned short* __restrict__ Wt)
{
  const int tid = blockIdx.x * 256 + threadIdx.x;  // 2 * 128 * 128 = 32768
  const int mat = tid >> 14;
  const int rr  = tid & 16383;
  const int f   = rr >> 7, c = rr & 127;
  const float x = (mat ? lw1 : lw0)[c * NC + f];
  const unsigned short h = f2bf(x);
  const unsigned short l = f2bf(x - bf2f(h));
  unsigned short* base = Wt + mat * 2 * (NC * NC);
  base[f * NC + c]           = h;
  base[NC * NC + f * NC + c] = l;
}

// ============================ fused kernel =====================================
// 512 thr = 8 waves = 8 nodes. Basis (R9 v2f) -> LDS bf16 hi/lo planes
// [mat=2m+hi/lo][16 rows][136 bf16 padded]; barrier; MFMA 32 tiles (16x16,
// K=128 in 4 chunks x 4 split-precision MFMA), 4 tiles/wave; rows 8..15 of
// each tile read garbage LDS but their D rows are discarded (row-separable).
#define MATS 2176   // 16*136 ushorts per matrix
__global__ __launch_bounds__(512) void epb_fused(
    const float* __restrict__ nf,      // [N, C, 9]
    const float* __restrict__ w1,      // [E, 2, C]
    const float* __restrict__ w2,      // [E, 9, C]
    const float* __restrict__ w3,      // [E, 51, C]
    const int*   __restrict__ species, // [N]
    const unsigned short* __restrict__ Wt,  // [4][128][128] bf16 (f-major)
    float* __restrict__ out)           // [N, F, 4]
{
  __shared__ unsigned short Ash[8 * MATS];   // 34.8 KB
  const int t    = threadIdx.x;
  const int nb   = blockIdx.x * 8;
  const int wave = t >> 6, lane = t & 63;

  // ========================= basis (wave = node) ===============================
  {
    const int nl = wave, c0 = lane * 2;
    const int n  = nb + nl;
    const int s  = species[n];

    const float* ap = nf + ((size_t)n * NC + c0) * 9;
    v2f A[9];
    sfor<9>([&](auto I) { A[I.value] = v2f{ap[I.value], ap[I.value + 9]}; });

    const float* w1p = w1 + (size_t)s * 2  * NC + c0;
    const float* w2p = w2 + (size_t)s * 9  * NC + c0;
    const float* w3p = w3 + (size_t)s * 51 * NC + c0;

    v2f B[4];
    {
      const v2f wa = ld2(w1p), wb = ld2(w1p + NC);
      B[0] = wa * A[0];
      B[1] = wb * A[1];
      B[2] = wb * A[2];
      B[3] = wb * A[3];
    }

    sfor<7>([&](auto P) {
      constexpr int p  = P.value;
      constexpr int l1 = P2U_L1c[p], l2 = P2U_L2c[p], lo = P2U_LOc[p];
      constexpr int d1 = 2*l1+1, d2 = 2*l2+1, dl = 2*lo+1;
      constexpr int off = T_OFFc[P2U_TBLc[p]];
      v2f w = ld2(w2p + P2U_WAc[p] * NC);
      if constexpr (P2U_WBc[p] >= 0) w = w + ld2(w2p + P2U_WBc[p] * NC);
      sfor<dl>([&](auto Kk) {
        constexpr int k = Kk.value;
        v2f v = {0.f, 0.f};
        sfor<d1>([&](auto I) {
          sfor<d2>([&](auto J) {
            constexpr float cgc = CG_ALL.v[off + (I.value * d2 + J.value) * dl + k];
            if constexpr (cgc != 0.0f) {
              constexpr int ia = AOFFc[l1] + I.value, ja = AOFFc[l2] + J.value;
              constexpr int x = ia < ja ? ia : ja, y = ia < ja ? ja : ia;
              v = cfma(cgc, A[x] * A[y], v);
            }
          });
        });
        B[lo + k] = vfma(w, v, B[lo + k]);
      });
    });

    sfor<13>([&](auto CI) {
      constexpr int tk  = CANONc[CI.value];
      constexpr int l1  = K_L1c[tk], l2 = K_L2c[tk], l12 = K_L12c[tk];
      constexpr int d1  = 2*l1+1, d2 = 2*l2+1, d12 = 2*l12+1;
      constexpr int off = T_OFFc[tk];
      v2f tt[d12];
      sfor<d12>([&](auto Kk) {
        constexpr int k = Kk.value;
        v2f v = {0.f, 0.f};
        sfor<d1>([&](auto I) {
          sfor<d2>([&](auto J) {
            constexpr float cgc = CG_ALL.v[off + (I.value * d2 + J.value) * d12 + k];
            if constexpr (cgc != 0.0f) {
              constexpr int ia = AOFFc[l1] + I.value, ja = AOFFc[l2] + J.value;
              constexpr int x = ia < ja ? ia : ja, y = ia < ja ? ja : ia;
              v = cfma(cgc, A[x] * A[y], v);
            }
          });
        });
        tt[k] = v;
      });

      auto consume = [&](auto TK, auto SG) {
        constexpr int tkey = TK.value;
        constexpr float sgn = (float)SG.value;
        constexpr int pcnt = P3_STARTc[tkey + 1] - P3_STARTc[tkey];
        sfor<pcnt>([&](auto PP) {
          constexpr int p  = P3_STARTc[tkey] + PP.value;
          constexpr int l3 = P3_L3c[p], lo = P3_LOc[p];
          constexpr int d3 = 2*l3+1, dl = 2*lo+1;
          constexpr int off2 = T_OFFc[P3_TBLc[p]];
          const v2f w = ld2(w3p + p * NC);
          sfor<dl>([&](auto M) {
            v2f v = {0.f, 0.f};
            sfor<d12>([&](auto Kk) {
              sfor<d3>([&](auto J) {
                constexpr float cgc = sgn * CG_ALL.v[off2 + (Kk.value * d3 + J.value) * dl + M.value];
                if constexpr (cgc != 0.0f)
                  v = cfma(cgc, tt[Kk.value] * A[AOFFc[l3] + J.value], v);
              });
            });
            B[lo + M.value] = vfma(w, v, B[lo + M.value]);
          });
        });
      };
      consume(std::integral_constant<int, tk>{}, std::integral_constant<int, 1>{});
      constexpr int td = CONS2c[CI.value];
      if constexpr (td >= 0)
        consume(std::integral_constant<int, td>{},
                std::integral_constant<int, (int)TT_SGNc[td]>{});
    });

    // epilogue -> LDS bf16 hi/lo planes (dword writes, bank-uniform via 136 pad)
    unsigned int* Au = reinterpret_cast<unsigned int*>(Ash);
    sfor<4>([&](auto M) {
      constexpr int m = M.value;
      const float x0 = B[m].x, x1 = B[m].y;
      const unsigned short h0 = f2bf(x0), h1 = f2bf(x1);
      const unsigned short l0 = f2bf(x0 - bf2f(h0)), l1 = f2bf(x1 - bf2f(h1));
      Au[(2*m)     * (MATS/2) + nl * 68 + lane] = ((unsigned int)h1 << 16) | h0;
      Au[(2*m + 1) * (MATS/2) + nl * 68 + lane] = ((unsigned int)l1 << 16) | l0;
    });
  }
  __syncthreads();

  // ========================= MFMA linear (4 tiles/wave) ========================
  const int row  = lane & 15;    // A: node-row / W: f-col
  const int quad = lane >> 4;
  const float s4 = 0.08838834764831845f;  // 1/sqrt(128)

  sfor<4>([&](auto TI) {
    const int tile = wave * 4 + TI.value;        // 0..31
    const int m    = tile >> 3;                  // plane
    const int f0   = (tile & 7) * 16;

    const unsigned short* Whi = Wt + (m == 0 ? 0 : 2) * (NC * NC);
    const unsigned short* Wlo = Whi + NC * NC;
    const unsigned short* wh = Whi + (f0 + row) * NC + quad * 8;
    const unsigned short* wl = Wlo + (f0 + row) * NC + quad * 8;

    const unsigned short* ah = Ash + (2*m)     * MATS + row * 136 + quad * 8;
    const unsigned short* al = Ash + (2*m + 1) * MATS + row * 136 + quad * 8;

    f32x4 acc = {0.f, 0.f, 0.f, 0.f};
    sfor<4>([&](auto KC) {
      constexpr int c0 = KC.value * 32;
      const bf16x8 a_h = *reinterpret_cast<const bf16x8*>(ah + c0);
      const bf16x8 a_l = *reinterpret_cast<const bf16x8*>(al + c0);
      const bf16x8 w_h = *reinterpret_cast<const bf16x8*>(wh + c0);
      const bf16x8 w_l = *reinterpret_cast<const bf16x8*>(wl + c0);
      acc = __builtin_amdgcn_mfma_f32_16x16x32_bf16(a_h, w_h, acc, 0, 0, 0);
      acc = __builtin_amdgcn_mfma_f32_16x16x32_bf16(a_h, w_l, acc, 0, 0, 0);
      acc = __builtin_amdgcn_mfma_f32_16x16x32_bf16(a_l, w_h, acc, 0, 0, 0);
      acc = __builtin_amdgcn_mfma_f32_16x16x32_bf16(a_l, w_l, acc, 0, 0, 0);
    });

    // C/D: col(lane&15)=f, row(quad*4+reg)=node-local; keep rows 0..7 only
    if (quad < 2) {
      const int f = f0 + row;
      sfor<4>([&](auto R) {
        const int nl2 = quad * 4 + R.value;      // 0..7
        out[(size_t)(nb + nl2) * 512 + f * 4 + m] = acc[R.value] * s4;
      });
    }
  });
}

// ------------------------------- launcher --------------------------------------
extern "C" void kernel_launch(void* const* d_in, const int* in_sizes, int n_in,
                              void* d_out, int out_size, void* d_ws, size_t ws_size,
                              hipStream_t stream) {
  const float* nf  = (const float*)d_in[0];
  const float* w1  = (const float*)d_in[1];
  const float* w2  = (const float*)d_in[2];
  const float* w3  = (const float*)d_in[3];
  const float* lw0 = (const float*)d_in[4];
  const float* lw1 = (const float*)d_in[5];
  const int*   spc = (const int*)  d_in[6];
  float* out = (float*)d_out;
  unsigned short* Wt = (unsigned short*)d_ws;   // 128 KB packed weights
  (void)ws_size; (void)in_sizes; (void)n_in; (void)out_size;

  hipLaunchKernelGGL(wt_pack, dim3(32768 / 256), dim3(256), 0, stream,
                     lw0, lw1, Wt);
  hipLaunchKernelGGL(epb_fused, dim3(NN / 8), dim3(512), 0, stream,
                     nf, w1, w2, w3, spc, Wt, out);
}